// Round 3
// baseline (6002.241 us; speedup 1.0000x reference)
//
#include <hip/hip_runtime.h>
#include <hip/hip_bf16.h>

#define B_   128
#define S_   512
#define I_   256
#define H_   256
#define G4   1024   // 4*H

// Journal R3: still no GPU (3x GPUAcquisitionTimeout). This round hardens
// correctness for the first real run:
//  - TIER system keyed on ws_size (constant across calls -> graph-safe):
//      0: fp32 xw in ws (258 MB)   1: bf16 xw (130 MB)   2: fused, no xw (2 MB)
//  - precise expf/tanhf activations (unknown fp32 absmax threshold; libm
//    costs ~10% of scan dot-loop, removes a validation-failure mode)
// Structure: prep -> [xw_gemm] -> lstm_scan (64 WGs x 2 batches, zero grid
// syncs; U streamed from XCD-local L2 each step; h double-buffered in LDS).

__device__ __forceinline__ float masked_noise(float u, float n, float r) {
    // masking.forward, mask_type='signed'  (EPS = 1e-8)
    float z = (u / (n + 1e-8f) + 1.0f) * 0.5f;
    float m = floorf(z + r);
    m = fminf(fmaxf(m, 0.0f), 1.0f);
    return n * (2.0f * m - 1.0f);
}

__device__ __forceinline__ float sigmoid_f(float x) {
    return 1.0f / (1.0f + expf(-x));
}
__device__ __forceinline__ float tanh_f(float x) {
    return tanhf(x);
}

// ---------------- prep: actual_W / actual_U, gate-interleaved ----------------
// out layout: a[(k*256 + j)*4 + g] = orig[k*1024 + g*256 + j]
// (column permutation; GEMM treats columns opaquely, scan reads float4/unit)
__global__ __launch_bounds__(256) void prep_kernel(
    const float* __restrict__ W,  const float* __restrict__ uW,
    const float* __restrict__ nW, const float* __restrict__ rW,
    const float* __restrict__ U,  const float* __restrict__ uU,
    const float* __restrict__ nU, const float* __restrict__ rU,
    float* __restrict__ aW4, float* __restrict__ aU4) {
    int idx = blockIdx.x * 256 + threadIdx.x;
    const int n = I_ * G4;  // 262144
    if (idx < n) {
        float v = W[idx] + masked_noise(uW[idx], nW[idx], rW[idx]);
        int k = idx >> 10, col = idx & 1023;
        int g = col >> 8, j = col & 255;
        aW4[((size_t)(k << 8) + j) * 4 + g] = v;
    } else {
        int i2 = idx - n;
        float v = U[i2] + masked_noise(uU[i2], nU[i2], rU[i2]);
        int k = i2 >> 10, col = i2 & 1023;
        int g = col >> 8, j = col & 255;
        aU4[((size_t)(k << 8) + j) * 4 + g] = v;
    }
}

// ---------------- xW = einsum('bsi,ig->sbg'), permuted columns ----------------
// Tile: 128 rows (all b, one s) x 64 cols, K chunks of 64. grid=(16,512).
template<int XW_BF16>
__global__ __launch_bounds__(256) void xw_gemm(
    const float* __restrict__ x, const float* __restrict__ aW4,
    void* __restrict__ xw_out) {
    __shared__ float xs[64][132];  // [kk][row]  (x tile, transposed)
    __shared__ float wt[64][68];   // [kk][col]
    const int tid = threadIdx.x;
    const int tx = tid & 15;        // col group of 4
    const int ty = tid >> 4;        // row group of 8
    const int bx = blockIdx.x;      // N tile (64 cols)
    const int s  = blockIdx.y;      // timestep

    float acc[8][4];
#pragma unroll
    for (int i = 0; i < 8; ++i)
#pragma unroll
        for (int j = 0; j < 4; ++j) acc[i][j] = 0.0f;

    for (int kc = 0; kc < 4; ++kc) {
#pragma unroll
        for (int t = 0; t < 8; ++t) {
            int e = tid + t * 256;           // 0..2047
            int row = e >> 4;                // b
            int kq  = e & 15;                // float4 index along k
            float4 v = *reinterpret_cast<const float4*>(
                &x[((size_t)row * S_ + s) * I_ + kc * 64 + kq * 4]);
            xs[kq * 4 + 0][row] = v.x;
            xs[kq * 4 + 1][row] = v.y;
            xs[kq * 4 + 2][row] = v.z;
            xs[kq * 4 + 3][row] = v.w;
        }
#pragma unroll
        for (int t = 0; t < 4; ++t) {
            int e = tid + t * 256;           // 0..1023
            int kk = e >> 4;
            int cq = e & 15;
            float4 v = *reinterpret_cast<const float4*>(
                &aW4[((size_t)(kc * 64 + kk)) * G4 + bx * 64 + cq * 4]);
            *reinterpret_cast<float4*>(&wt[kk][cq * 4]) = v;
        }
        __syncthreads();

#pragma unroll 8
        for (int kk = 0; kk < 64; ++kk) {
            float4 a0 = *reinterpret_cast<const float4*>(&xs[kk][ty * 8]);
            float4 a1 = *reinterpret_cast<const float4*>(&xs[kk][ty * 8 + 4]);
            float4 bv = *reinterpret_cast<const float4*>(&wt[kk][tx * 4]);
            float a[8] = {a0.x, a0.y, a0.z, a0.w, a1.x, a1.y, a1.z, a1.w};
            float b[4] = {bv.x, bv.y, bv.z, bv.w};
#pragma unroll
            for (int i = 0; i < 8; ++i)
#pragma unroll
                for (int j = 0; j < 4; ++j) acc[i][j] += a[i] * b[j];
        }
        __syncthreads();
    }

#pragma unroll
    for (int i = 0; i < 8; ++i) {
        int row = ty * 8 + i;  // b
        size_t off = ((size_t)s * B_ + row) * G4 + bx * 64 + tx * 4;
        if (XW_BF16) {
            __hip_bfloat16* xwb = (__hip_bfloat16*)xw_out;
            alignas(8) __hip_bfloat16 tmp[4];
#pragma unroll
            for (int j = 0; j < 4; ++j) tmp[j] = __float2bfloat16(acc[i][j]);
            *reinterpret_cast<ushort4*>(&xwb[off]) =
                *reinterpret_cast<const ushort4*>(tmp);
        } else {
            float* xwf = (float*)xw_out;
            float4 v = {acc[i][0], acc[i][1], acc[i][2], acc[i][3]};
            *reinterpret_cast<float4*>(&xwf[off]) = v;
        }
    }
}

// ---------------- sequential LSTM scan ----------------
// 64 blocks x 256 threads; block owns batches {2*bid, 2*bid+1}.
// Thread j owns hidden unit j for both batches. Per k: one float4 U load
// ({i,f,g,o} interleaved), one broadcast ds_read_b64 for (h0,h1).
// TIER: 0 = fp32 xw, 1 = bf16 xw, 2 = fused (recompute x@W per step).
template<int TIER>
__global__ __launch_bounds__(256) void lstm_scan(
    const void* __restrict__ xw_in, const float* __restrict__ aU4,
    const float* __restrict__ aW4, const float* __restrict__ x,
    float* __restrict__ out) {
    const int j  = threadIdx.x;
    const int b0 = blockIdx.x * 2;
    __shared__ float hbuf[2][H_][2];   // [buf][k][bb]
    __shared__ float xsh[I_][2];       // TIER2: x[b][s][k] staged per step

    hbuf[0][j][0] = 0.0f;
    hbuf[0][j][1] = 0.0f;
    float c0 = 0.0f, c1 = 0.0f;
    float h0l = 0.0f, h1l = 0.0f;
    __syncthreads();

    const float*          xwf = (const float*)xw_in;
    const __hip_bfloat16* xwb = (const __hip_bfloat16*)xw_in;

    for (int s = 0; s < S_; ++s) {
        const int cur = s & 1;
        float4 a0 = {0.f, 0.f, 0.f, 0.f};   // i,f,g,o for batch b0
        float4 a1 = {0.f, 0.f, 0.f, 0.f};   // for batch b0+1

        if (TIER == 2) {
            // stage x rows for this step, then fold x@W into the dot loop
            xsh[j][0] = x[((size_t)b0 * S_ + s) * I_ + j];
            xsh[j][1] = x[((size_t)(b0 + 1) * S_ + s) * I_ + j];
            __syncthreads();
#pragma unroll 8
            for (int k = 0; k < H_; ++k) {
                float2 h  = *reinterpret_cast<const float2*>(&hbuf[cur][k][0]);
                float2 xv = *reinterpret_cast<const float2*>(&xsh[k][0]);
                float4 u = *reinterpret_cast<const float4*>(
                    &aU4[((size_t)k << 10) + (j << 2)]);
                float4 w = *reinterpret_cast<const float4*>(
                    &aW4[((size_t)k << 10) + (j << 2)]);
                a0.x += h.x * u.x + xv.x * w.x;
                a0.y += h.x * u.y + xv.x * w.y;
                a0.z += h.x * u.z + xv.x * w.z;
                a0.w += h.x * u.w + xv.x * w.w;
                a1.x += h.y * u.x + xv.y * w.x;
                a1.y += h.y * u.y + xv.y * w.y;
                a1.z += h.y * u.z + xv.y * w.z;
                a1.w += h.y * u.w + xv.y * w.w;
            }
        } else {
#pragma unroll 16
            for (int k = 0; k < H_; ++k) {
                float2 h = *reinterpret_cast<const float2*>(&hbuf[cur][k][0]);
                float4 u = *reinterpret_cast<const float4*>(
                    &aU4[((size_t)k << 10) + (j << 2)]);
                a0.x += h.x * u.x; a0.y += h.x * u.y;
                a0.z += h.x * u.z; a0.w += h.x * u.w;
                a1.x += h.y * u.x; a1.y += h.y * u.y;
                a1.z += h.y * u.z; a1.w += h.y * u.w;
            }
        }

        float4 x0 = {0.f, 0.f, 0.f, 0.f}, x1 = {0.f, 0.f, 0.f, 0.f};
        if (TIER == 0) {
            size_t xoff = ((size_t)s * B_ + b0) * G4 + (j << 2);
            x0 = *reinterpret_cast<const float4*>(&xwf[xoff]);
            x1 = *reinterpret_cast<const float4*>(&xwf[xoff + G4]);
        } else if (TIER == 1) {
            size_t xoff = ((size_t)s * B_ + b0) * G4 + (j << 2);
            ushort4 r0 = *reinterpret_cast<const ushort4*>(&xwb[xoff]);
            ushort4 r1 = *reinterpret_cast<const ushort4*>(&xwb[xoff + G4]);
            x0.x = __uint_as_float((unsigned)r0.x << 16);
            x0.y = __uint_as_float((unsigned)r0.y << 16);
            x0.z = __uint_as_float((unsigned)r0.z << 16);
            x0.w = __uint_as_float((unsigned)r0.w << 16);
            x1.x = __uint_as_float((unsigned)r1.x << 16);
            x1.y = __uint_as_float((unsigned)r1.y << 16);
            x1.z = __uint_as_float((unsigned)r1.z << 16);
            x1.w = __uint_as_float((unsigned)r1.w << 16);
        }

        // batch 0
        {
            float it = sigmoid_f(x0.x + a0.x);
            float ft = sigmoid_f(x0.y + a0.y);
            float gt = tanh_f(x0.z + a0.z);
            float ot = sigmoid_f(x0.w + a0.w);
            c0 = ft * c0 + it * gt;
            h0l = ot * tanh_f(c0);
            out[((size_t)b0 * S_ + s) * H_ + j] = h0l;
        }
        // batch 1
        {
            float it = sigmoid_f(x1.x + a1.x);
            float ft = sigmoid_f(x1.y + a1.y);
            float gt = tanh_f(x1.z + a1.z);
            float ot = sigmoid_f(x1.w + a1.w);
            c1 = ft * c1 + it * gt;
            h1l = ot * tanh_f(c1);
            out[((size_t)(b0 + 1) * S_ + s) * H_ + j] = h1l;
        }
        float2 hw = {h0l, h1l};
        *reinterpret_cast<float2*>(&hbuf[cur ^ 1][j][0]) = hw;
        __syncthreads();
    }

    const size_t HS = (size_t)B_ * S_ * H_;          // 16777216
    const size_t CS = (size_t)B_ * H_;               // 32768
    out[HS + (size_t)b0 * H_ + j]            = h0l;
    out[HS + (size_t)(b0 + 1) * H_ + j]      = h1l;
    out[HS + CS + (size_t)b0 * H_ + j]       = c0;
    out[HS + CS + (size_t)(b0 + 1) * H_ + j] = c1;
}

// ---------------- launch ----------------
extern "C" void kernel_launch(void* const* d_in, const int* in_sizes, int n_in,
                              void* d_out, int out_size, void* d_ws, size_t ws_size,
                              hipStream_t stream) {
    const float* x  = (const float*)d_in[0];
    const float* W  = (const float*)d_in[1];
    const float* U  = (const float*)d_in[2];
    const float* uW = (const float*)d_in[3];
    const float* nW = (const float*)d_in[4];
    const float* rW = (const float*)d_in[5];
    const float* uU = (const float*)d_in[6];
    const float* nU = (const float*)d_in[7];
    const float* rU = (const float*)d_in[8];

    float* ws  = (float*)d_ws;
    float* aW4 = ws;                       // 262144 floats
    float* aU4 = ws + 262144;              // 262144 floats
    void*  xw  = (void*)(ws + 524288);     // S*B*4H elems (fp32 or bf16)

    const size_t xw_elems  = (size_t)S_ * B_ * G4;            // 67108864
    const size_t need_fp32 = (524288 + xw_elems) * 4;         // ~258 MB
    const size_t need_bf16 = 524288 * 4 + xw_elems * 2;       // ~130 MB

    prep_kernel<<<2048, 256, 0, stream>>>(W, uW, nW, rW, U, uU, nU, rU, aW4, aU4);

    dim3 ggrid(16, 512);
    if (ws_size >= need_fp32) {
        xw_gemm<0><<<ggrid, 256, 0, stream>>>(x, aW4, xw);
        lstm_scan<0><<<64, 256, 0, stream>>>(xw, aU4, aW4, x, (float*)d_out);
    } else if (ws_size >= need_bf16) {
        xw_gemm<1><<<ggrid, 256, 0, stream>>>(x, aW4, xw);
        lstm_scan<1><<<64, 256, 0, stream>>>(xw, aU4, aW4, x, (float*)d_out);
    } else {
        lstm_scan<2><<<64, 256, 0, stream>>>(nullptr, aU4, aW4, x, (float*)d_out);
    }
}